// Round 5
// baseline (156.036 us; speedup 1.0000x reference)
//
#include <hip/hip_runtime.h>
#include <stdint.h>

// out[b,j,:] = sym[b,j,:] + sum_{i!=j} (sym[b,i,:] @ W[rel(i,j)].T + bias[rel(i,j)])
// B=8, N=1024, D=128, 6 relations.
//
// Linearity rewrite:  agg[j] = sum_r (sum_{i!=j, rel=r} sym[i]) @ W[r].T + cnt_r(j)*bias[r]
//
// R15 (MEASUREMENT ROUND): math identical to R14. The fused body runs REP=3
// times inside one dispatch (rep-isolating barrier, pragma unroll 1).
// Purpose: four structurally different fused kernels (R10..R14) all produced
// total ~93-95us; fused is pinned invisibly just below the harness's 40.8us
// 256MiB poison fills. Channels:
//   (1) total_new - 95.4 = 2*F  ->  F = true fused duration (+-1.5us)
//   (2) if F >= ~14us, the 3F dispatch enters rocprof top-5 WITH counters
//       (MfmaUtil / VALUBusy / LDS conflicts / FETCH) for the real kernel.
// Pre-committed forks: F~40 -> counter-driven ablation next round (REP back
// to 1). F~12-15 -> fused already near floor; the hidden ~25-30us is
// prep/gaps/overhead -> attack dispatch structure instead.

typedef __attribute__((ext_vector_type(8))) short bf16x8;
typedef __attribute__((ext_vector_type(4))) float f32x4;
union U4B { uint4 u; bf16x8 b; };

#if defined(__has_builtin)
#  if __has_builtin(__builtin_amdgcn_global_load_lds)
#    define HAVE_GLL 1
#  endif
#  if __has_builtin(__builtin_amdgcn_mul_u24)
#    define OH_MUL24 1
#  endif
#endif

#define REP 3   // measurement multiplier; revert to 1 after this round

__device__ __forceinline__ uint16_t f2bf(float f) {
    union { float f; uint32_t u; } v; v.f = f;
    uint32_t u = v.u;
    uint32_t r = (u + 0x7FFFu + ((u >> 16) & 1u)) >> 16;  // RNE
    return (uint16_t)r;
}

// raw barrier: orders LDS only; never drains vmcnt (DMA stays in flight).
#define BARRIER_LGKM() do {                                   \
    asm volatile("s_waitcnt lgkmcnt(0)" ::: "memory");        \
    __builtin_amdgcn_s_barrier();                             \
    asm volatile("" ::: "memory");                            \
} while (0)

// ---------------------------------------------------------------------------
// prep: blocks 0..255: transpose X[b][i][e] fp32 -> symT[b][e][i] bf16 (64x64)
//       blocks 256..351: W[r][ep][e] fp32 -> WtB blocked bf16
//       blocks 352..383: T4[b][qq][e] = sum_{i in qq*256..+256} X[b][i][e]
// ---------------------------------------------------------------------------
__global__ __launch_bounds__(256)
void prep_kernel(const float* __restrict__ X, const float* __restrict__ W,
                 uint16_t* __restrict__ symT, uint16_t* __restrict__ WtB,
                 float* __restrict__ T4) {
    const int blk = blockIdx.x, tid = threadIdx.x;
    if (blk < 256) {
        __shared__ float T[64 * 65];
        const int b = blk & 7, z = blk >> 3, it = z & 15, et = z >> 4;
        const int i0 = it * 64, e0 = et * 64;
        const float4* Xf = (const float4*)X;
#pragma unroll
        for (int s = 0; s < 4; ++s) {
            int il = s * 16 + (tid >> 4), e4 = tid & 15;
            float4 v = Xf[((size_t)b << 15) + (size_t)((i0 + il) << 5) + (e0 >> 2) + e4];
            T[il * 65 + e4 * 4 + 0] = v.x;
            T[il * 65 + e4 * 4 + 1] = v.y;
            T[il * 65 + e4 * 4 + 2] = v.z;
            T[il * 65 + e4 * 4 + 3] = v.w;
        }
        __syncthreads();
#pragma unroll
        for (int s = 0; s < 4; ++s) {
            int el = s * 16 + (tid >> 4), il4 = tid & 15;
            uint16_t h0 = f2bf(T[(il4 * 4 + 0) * 65 + el]);
            uint16_t h1 = f2bf(T[(il4 * 4 + 1) * 65 + el]);
            uint16_t h2 = f2bf(T[(il4 * 4 + 2) * 65 + el]);
            uint16_t h3 = f2bf(T[(il4 * 4 + 3) * 65 + el]);
            uint2 pk = { (uint32_t)h0 | ((uint32_t)h1 << 16),
                         (uint32_t)h2 | ((uint32_t)h3 << 16) };
            *(uint2*)&symT[((size_t)b << 17) + ((size_t)(e0 + el) << 10) + i0 + il4 * 4] = pk;
        }
    } else if (blk < 352) {
        int g = (blk - 256) * 256 + tid;          // 0..24575 float4s of W
        float4 v = ((const float4*)W)[g];
        int r = g >> 12, rem = g & 4095, ep = rem >> 5, e4 = rem & 31;
        int kb = r * 4 + (e4 >> 3);               // k = r*128 + e4*4+t
        int kc = (e4 & 7) * 4;
        uint16_t h0 = f2bf(v.x), h1 = f2bf(v.y), h2 = f2bf(v.z), h3 = f2bf(v.w);
        uint2 pk = { (uint32_t)h0 | ((uint32_t)h1 << 16),
                     (uint32_t)h2 | ((uint32_t)h3 << 16) };
        *(uint2*)&WtB[((size_t)(kb * 128 + ep)) * 32 + kc] = pk;
    } else {
        // T4: per-b quarter column sums (fp32), 32 blocks = (b, quarter)
        const int z = blk - 352, bb = z >> 2, qq = z & 3;
        const int e = tid & 127, half = tid >> 7;
        const float* base = X + (((size_t)(bb << 10) + (qq << 8) + (half << 7)) << 7) + e;
        float s = 0.f;
#pragma unroll 8
        for (int itr = 0; itr < 128; ++itr) s += base[(size_t)itr << 7];
        __shared__ float red[256];
        red[tid] = s;
        __syncthreads();
        if (tid < 128) T4[(z << 7) + tid] = red[tid] + red[tid + 128];
    }
}

// ---------------------------------------------------------------------------
// fused kernel: grid 512 = 8b x 64jt (16 j per block), 512 thr = 8 waves.
// LDS map (49536 B):
//   @0      B double buffer: 2 x 16384 (64-i chunk; wave w owns [w*2048,+2048):
//           16 e-rows x 128 B, 16B segs XOR-swizzled seg' = seg ^ (e&7)).
//           buf1 head (@16384, 8KB) doubles as posS during classify.
//           After phase 2 the region holds SA: 16 j-rows x 768 k bf16,
//           row stride SP=776 halfwords (24832 B).
//   @32768  rel32: 16 j x 256 dwords, dword-index XOR swizzle (d ^ 2j), 16KB.
//   @49152  cntL: 16 j x 6 relations, float, 384 B.
// ---------------------------------------------------------------------------
#define SP 776

__global__ __launch_bounds__(512, 4)
void fused_kernel(const float* __restrict__ X, const float* __restrict__ pos,
                  const uint16_t* __restrict__ symT, const uint16_t* __restrict__ WtB,
                  const float* __restrict__ bias, const float* __restrict__ T4,
                  float* __restrict__ out) {
    __shared__ __align__(16) char smem[49536];
    float2*   posS  = (float2*)(smem + 16384);
    uint16_t* SA    = (uint16_t*)smem;
    uint32_t* rel32 = (uint32_t*)(smem + 32768);
    float*    cntL  = (float*)(smem + 49152);

    const int blk = blockIdx.x;
    const int b = blk & 7, jt = blk >> 3, j0 = jt * 16;
    const int tid = threadIdx.x;
    const int w = tid >> 6, lane = tid & 63, m = lane & 15, q = lane >> 4;

    const uint16_t* symTb = symT + ((size_t)b << 17);

    // --- B staging: wave w DMAs its own 16 e-rows, 64-i chunks, 2 issues ---
    int goff[2];
#pragma unroll
    for (int s = 0; s < 2; ++s) {
        int e = (w << 4) + (s << 3) + (lane >> 3);
        int t = lane & 7;
        goff[s] = (e << 10) + ((t ^ (e & 7)) << 3);   // halfword units; + c*64
    }

    auto issue_chunk = [&](int cidx, int bufsel) {
#ifdef HAVE_GLL
#pragma unroll
        for (int s = 0; s < 2; ++s) {
            const uint16_t* gp = symTb + goff[s] + cidx * 64;
            char* lp = smem + bufsel * 16384 + (w << 11) + (s << 10);  // wave-uniform
            typedef const __attribute__((address_space(1))) uint32_t gu32;
            typedef __attribute__((address_space(3))) uint32_t lu32;
            __builtin_amdgcn_global_load_lds((gu32*)gp, (lu32*)lp, 16, 0, 0);
        }
#else
#pragma unroll
        for (int s = 0; s < 2; ++s) {
            uint4 v = *(const uint4*)(symTb + goff[s] + cidx * 64);
            *(uint4*)(smem + bufsel * 16384 + (w << 11) + (s << 10) + lane * 16) = v;
        }
#endif
    };

#pragma unroll 1
    for (int rep = 0; rep < REP; ++rep) {
        // isolate reps: all phase-3 reads of SA/buf regions complete before
        // this rep re-stages posS / issues chunk-0 DMA into the same bytes.
        BARRIER_LGKM();

        // ---- phase 0: chunk-0 DMA in flight under classify; stage positions
        issue_chunk(0, 0);
        const float2* pos2 = (const float2*)pos + ((size_t)b << 10);
        float2 p0 = pos2[tid], p1 = pos2[tid + 512];
        posS[tid] = p0;
        posS[tid + 512] = p1;
        BARRIER_LGKM();

        // ---- phase 1: classify 16 j x 1024 i -> one-hot bytes (0 on diag) --
        {
            const int mm = tid & 15, grp = tid >> 4;    // grp 0..31: 32 i's each
            const int j = j0 + mm;
            const float2 pj = posS[j];
            uint32_t* dst = &rel32[mm * 256];
            const int sw = mm * 2;                      // dword-index XOR swizzle
#pragma unroll
            for (int s = 0; s < 8; ++s) {
                uint32_t word = 0;
#pragma unroll
                for (int qq = 0; qq < 4; ++qq) {
                    int i = grp * 32 + s * 4 + qq;
                    float2 pi = posS[i];
                    float dx = pj.x - pi.x, dy = pj.y - pi.y;
                    // faithful priority chain of _get_relation_type
                    int r = (dy > 0.5f) ? 0
                          : (dy < -0.5f) ? 1
                          : (dx < -0.5f) ? 2
                          : (dx > 0.5f)  ? 3
                          : (fabsf(dx) < 0.3f && fabsf(dy) < 0.3f) ? 4
                          : 5;
                    uint32_t oh = (i == j) ? 0u : (1u << r);
                    word |= oh << (8 * qq);
                }
                dst[(grp * 8 + s) ^ sw] = word;
            }
        }
        BARRIER_LGKM();            // rel32 ready; posS dead

        // ---- counts: cnt_r(j) from rel32; cnt5 = 1023 - sum ----
        {
            const int j = tid >> 5, t = tid & 31;
            const uint32_t* row = &rel32[j * 256 + t * 8];
            uint32_t s0 = 0, s1 = 0, s2 = 0, s3 = 0, s4 = 0;
#pragma unroll
            for (int k = 0; k < 8; ++k) {
                uint32_t wd = row[k];
                s0 += wd & 0x01010101u;        s1 += (wd >> 1) & 0x01010101u;
                s2 += (wd >> 2) & 0x01010101u; s3 += (wd >> 3) & 0x01010101u;
                s4 += (wd >> 4) & 0x01010101u;
            }
            int cnt[6];
            cnt[0] = (int)((s0 * 0x01010101u) >> 24);
            cnt[1] = (int)((s1 * 0x01010101u) >> 24);
            cnt[2] = (int)((s2 * 0x01010101u) >> 24);
            cnt[3] = (int)((s3 * 0x01010101u) >> 24);
            cnt[4] = (int)((s4 * 0x01010101u) >> 24);
#pragma unroll
            for (int off = 1; off < 32; off <<= 1)
#pragma unroll
                for (int r = 0; r < 5; ++r)
                    cnt[r] += __shfl_xor(cnt[r], off, 64);   // 32-aligned groups
            if (t == 0) {
#pragma unroll
                for (int r = 0; r < 5; ++r) cntL[j * 6 + r] = (float)cnt[r];
                cntL[j * 6 + 5] = (float)(1023 - cnt[0] - cnt[1] - cnt[2] - cnt[3] - cnt[4]);
            }
        }

        // ---- phase 2: masked GEMM, 16 chunks of 64 i, barrier-free ----
        f32x4 acc[5];
#pragma unroll
        for (int r = 0; r < 5; ++r) acc[r] = (f32x4){0.f, 0.f, 0.f, 0.f};

        const int E = (w << 4) + m;          // e-row owned by this lane
        const int bseg0 = q ^ (m & 7);
        const int bseg1 = (4 + q) ^ (m & 7);
        const int csw = m << 1;

        for (int c = 0; c < 16; ++c) {
            if (c < 15) {
                issue_chunk(c + 1, (c + 1) & 1);              // prefetch next chunk
                asm volatile("s_waitcnt vmcnt(2)" ::: "memory");  // chunk c landed
            } else {
                asm volatile("s_waitcnt vmcnt(0)" ::: "memory");
            }
            const char* bb = smem + (c & 1) * 16384 + (w << 11) + (m << 7);
#pragma unroll
            for (int ks = 0; ks < 2; ++ks) {
                U4B bfr;
                bfr.u = *(const uint4*)(bb + ((ks ? bseg1 : bseg0) << 4));
                uint2 cw = *(const uint2*)&rel32[m * 256 +
                               (((c << 4) + (ks << 3) + (q << 1)) ^ csw)];
                uint32_t hx01 = __builtin_amdgcn_perm(cw.x, cw.x, 0x01010000u) & 0x00FF00FFu;
                uint32_t hx23 = __builtin_amdgcn_perm(cw.x, cw.x, 0x03030202u) & 0x00FF00FFu;
                uint32_t hy01 = __builtin_amdgcn_perm(cw.y, cw.y, 0x01010000u) & 0x00FF00FFu;
                uint32_t hy23 = __builtin_amdgcn_perm(cw.y, cw.y, 0x03030202u) & 0x00FF00FFu;
#pragma unroll
                for (int r = 0; r < 5; ++r) {
                    const uint32_t rm = 0x00010001u << r;
                    U4B a;
#ifdef OH_MUL24
                    const uint32_t mc = 0x3F80u >> r;   // 2^r * mc == 0x3F80 (bf16 1.0)
                    a.u.x = (uint32_t)__builtin_amdgcn_mul_u24((int)(hx01 & rm), (int)mc);
                    a.u.y = (uint32_t)__builtin_amdgcn_mul_u24((int)(hx23 & rm), (int)mc);
                    a.u.z = (uint32_t)__builtin_amdgcn_mul_u24((int)(hy01 & rm), (int)mc);
                    a.u.w = (uint32_t)__builtin_amdgcn_mul_u24((int)(hy23 & rm), (int)mc);
#else
                    uint32_t g2;
                    g2 = hx01 & rm; a.u.x = (g2 << (14 - r)) - (g2 << (7 - r));
                    g2 = hx23 & rm; a.u.y = (g2 << (14 - r)) - (g2 << (7 - r));
                    g2 = hy01 & rm; a.u.z = (g2 << (14 - r)) - (g2 << (7 - r));
                    g2 = hy23 & rm; a.u.w = (g2 << (14 - r)) - (g2 << (7 - r));
#endif
                    acc[r] = __builtin_amdgcn_mfma_f32_16x16x32_bf16(a.b, bfr.b, acc[r], 0, 0, 0);
                }
            }
            // no barrier: wave only touches its own buffer regions.
        }
        BARRIER_LGKM();   // all waves done with B buffers before SA overwrites

        // ---- S -> LDS (bf16) + S5 complement ----
#pragma unroll
        for (int r = 0; r < 5; ++r)
#pragma unroll
            for (int reg = 0; reg < 4; ++reg)
                SA[(q * 4 + reg) * SP + r * 128 + E] = f2bf(acc[r][reg]);
        {
            float ts = T4[((b << 2) + 0) * 128 + E] + T4[((b << 2) + 1) * 128 + E]
                     + T4[((b << 2) + 2) * 128 + E] + T4[((b << 2) + 3) * 128 + E];
#pragma unroll
            for (int reg = 0; reg < 4; ++reg) {
                float symj = X[((size_t)((b << 10) + j0 + (q << 2) + reg) << 7) + E];
                float s5 = ts - symj
                         - acc[0][reg] - acc[1][reg] - acc[2][reg] - acc[3][reg] - acc[4][reg];
                SA[(q * 4 + reg) * SP + 5 * 128 + E] = f2bf(s5);
            }
        }
        BARRIER_LGKM();

        // ---- phase 3: wave w owns e-slice [w*16,+16); full K=768 ----
        {
            f32x4 c3 = (f32x4){0.f, 0.f, 0.f, 0.f};
#pragma unroll
            for (int kb = 0; kb < 24; ++kb) {
                U4B af, bw;
                af.u = *(const uint4*)&SA[m * SP + kb * 32 + q * 8];
                bw.u = *(const uint4*)&WtB[((size_t)(kb * 128 + (w << 4) + m)) * 32 + q * 8];
                c3 = __builtin_amdgcn_mfma_f32_16x16x32_bf16(af.b, bw.b, c3, 0, 0, 0);
            }

            // ---- epilogue: + sym + cnt_r*bias, direct store ----
            const int e = (w << 4) + m;
            float be[6];
#pragma unroll
            for (int r = 0; r < 6; ++r) be[r] = bias[r * 128 + e];
#pragma unroll
            for (int reg = 0; reg < 4; ++reg) {
                const int j = q * 4 + reg;
                float add = c3[reg];
#pragma unroll
                for (int r = 0; r < 6; ++r) add += cntL[j * 6 + r] * be[r];
                size_t o = ((size_t)((b << 10) + j0 + j) << 7) + e;
                out[o] = X[o] + add;
            }
        }
    }
}

extern "C" void kernel_launch(void* const* d_in, const int* in_sizes, int n_in,
                              void* d_out, int out_size, void* d_ws, size_t ws_size,
                              hipStream_t stream) {
    const float* symbols   = (const float*)d_in[0];  // [8,1024,128]
    const float* positions = (const float*)d_in[1];  // [8,1024,2]
    const float* W         = (const float*)d_in[2];  // [6,128,128]
    const float* bias      = (const float*)d_in[3];  // [6,128]
    float* out             = (float*)d_out;          // [8,1024,128]

    char* ws = (char*)d_ws;
    uint16_t* symT = (uint16_t*)ws;                  // 8*128*1024 bf16 = 2,097,152 B
    uint16_t* WtB  = (uint16_t*)(ws + 2097152);      // 24*128*32 bf16 =   196,608 B
    float*    T4   = (float*)(ws + 2097152 + 196608);// 8*4*128 f32    =    16,384 B

    prep_kernel<<<384, 256, 0, stream>>>(symbols, W, symT, WtB, T4);
    fused_kernel<<<512, 512, 0, stream>>>(symbols, positions, symT, WtB, bias, T4, out);
}

// Round 8
// 111.706 us; speedup vs baseline: 1.3969x; 1.3969x over previous
//
#include <hip/hip_runtime.h>
#include <stdint.h>

// out[b,j,:] = sym[b,j,:] + sum_{i!=j} (sym[b,i,:] @ W[rel(i,j)].T + bias[rel(i,j)])
// B=8, N=1024, D=128, 6 relations.
//
// Linearity rewrite:  agg[j] = sum_r (sum_{i!=j, rel=r} sym[i]) @ W[r].T + cnt_r(j)*bias[r]
//
// R18: back to the R14-PROVEN algebra (R16/R17's i-split was both buggy and,
// on recount, perf-neutral: same 160 MFMA / 16-chunk serial chain per wave).
// R15's measurement: F~35us, all pipes <30% real-busy, >=45% stall =>
// latency-bound with TLP capped by the GRID (512 blocks = 2 blocks/CU).
// This round raises TLP only:
//   - grid 1024: 8 j per block (j0 = jt*8). Inner loops byte-identical to
//     R14; MFMA rows 8..15 run duplicate masks via (m&7) aliasing (finite,
//     never stored). classify/count/tail halve per block.
//   - LDS exactly 40960 B (rel32 -> 8 rows @32768; counts computed AFTER
//     phase 2 into dead staging region @24832) -> 4 blocks/CU.
//   - __launch_bounds__(512,8): VGPR<=64 (R14 compiled at 64) -> 8 waves/SIMD.
//   => up to 32 waves/CU (2x TLP); worst case 3 blocks/CU (+50%).

typedef __attribute__((ext_vector_type(8))) short bf16x8;
typedef __attribute__((ext_vector_type(4))) float f32x4;
union U4B { uint4 u; bf16x8 b; };

#if defined(__has_builtin)
#  if __has_builtin(__builtin_amdgcn_global_load_lds)
#    define HAVE_GLL 1
#  endif
#  if __has_builtin(__builtin_amdgcn_mul_u24)
#    define OH_MUL24 1
#  endif
#endif

__device__ __forceinline__ uint16_t f2bf(float f) {
    union { float f; uint32_t u; } v; v.f = f;
    uint32_t u = v.u;
    uint32_t r = (u + 0x7FFFu + ((u >> 16) & 1u)) >> 16;  // RNE
    return (uint16_t)r;
}

// raw barrier: orders LDS only; never drains vmcnt (DMA stays in flight).
#define BARRIER_LGKM() do {                                   \
    asm volatile("s_waitcnt lgkmcnt(0)" ::: "memory");        \
    __builtin_amdgcn_s_barrier();                             \
    asm volatile("" ::: "memory");                            \
} while (0)

// ---------------------------------------------------------------------------
// prep: blocks 0..255: transpose X[b][i][e] fp32 -> symT[b][e][i] bf16 (64x64)
//       blocks 256..351: W[r][ep][e] fp32 -> WtB blocked bf16
//       blocks 352..383: T4[b][qq][e] = sum_{i in qq*256..+256} X[b][i][e]
// ---------------------------------------------------------------------------
__global__ __launch_bounds__(256)
void prep_kernel(const float* __restrict__ X, const float* __restrict__ W,
                 uint16_t* __restrict__ symT, uint16_t* __restrict__ WtB,
                 float* __restrict__ T4) {
    const int blk = blockIdx.x, tid = threadIdx.x;
    if (blk < 256) {
        __shared__ float T[64 * 65];
        const int b = blk & 7, z = blk >> 3, it = z & 15, et = z >> 4;
        const int i0 = it * 64, e0 = et * 64;
        const float4* Xf = (const float4*)X;
#pragma unroll
        for (int s = 0; s < 4; ++s) {
            int il = s * 16 + (tid >> 4), e4 = tid & 15;
            float4 v = Xf[((size_t)b << 15) + (size_t)((i0 + il) << 5) + (e0 >> 2) + e4];
            T[il * 65 + e4 * 4 + 0] = v.x;
            T[il * 65 + e4 * 4 + 1] = v.y;
            T[il * 65 + e4 * 4 + 2] = v.z;
            T[il * 65 + e4 * 4 + 3] = v.w;
        }
        __syncthreads();
#pragma unroll
        for (int s = 0; s < 4; ++s) {
            int el = s * 16 + (tid >> 4), il4 = tid & 15;
            uint16_t h0 = f2bf(T[(il4 * 4 + 0) * 65 + el]);
            uint16_t h1 = f2bf(T[(il4 * 4 + 1) * 65 + el]);
            uint16_t h2 = f2bf(T[(il4 * 4 + 2) * 65 + el]);
            uint16_t h3 = f2bf(T[(il4 * 4 + 3) * 65 + el]);
            uint2 pk = { (uint32_t)h0 | ((uint32_t)h1 << 16),
                         (uint32_t)h2 | ((uint32_t)h3 << 16) };
            *(uint2*)&symT[((size_t)b << 17) + ((size_t)(e0 + el) << 10) + i0 + il4 * 4] = pk;
        }
    } else if (blk < 352) {
        int g = (blk - 256) * 256 + tid;          // 0..24575 float4s of W
        float4 v = ((const float4*)W)[g];
        int r = g >> 12, rem = g & 4095, ep = rem >> 5, e4 = rem & 31;
        int kb = r * 4 + (e4 >> 3);               // k = r*128 + e4*4+t
        int kc = (e4 & 7) * 4;
        uint16_t h0 = f2bf(v.x), h1 = f2bf(v.y), h2 = f2bf(v.z), h3 = f2bf(v.w);
        uint2 pk = { (uint32_t)h0 | ((uint32_t)h1 << 16),
                     (uint32_t)h2 | ((uint32_t)h3 << 16) };
        *(uint2*)&WtB[((size_t)(kb * 128 + ep)) * 32 + kc] = pk;
    } else {
        // T4: per-b quarter column sums (fp32), 32 blocks = (b, quarter)
        const int z = blk - 352, bb = z >> 2, qq = z & 3;
        const int e = tid & 127, half = tid >> 7;
        const float* base = X + (((size_t)(bb << 10) + (qq << 8) + (half << 7)) << 7) + e;
        float s = 0.f;
#pragma unroll 8
        for (int itr = 0; itr < 128; ++itr) s += base[(size_t)itr << 7];
        __shared__ float red[256];
        red[tid] = s;
        __syncthreads();
        if (tid < 128) T4[(z << 7) + tid] = red[tid] + red[tid + 128];
    }
}

// ---------------------------------------------------------------------------
// fused kernel: grid 1024 = 8b x 128jt (8 j per block), 512 thr = 8 waves.
// LDS map (40960 B -> 4 blocks/CU; 3 if pool reserved):
//   @0      B double buffer: 2 x 16384 (64-i chunk; wave w owns [w*2048,+2048):
//           16 e-rows x 128 B, 16B segs XOR-swizzled seg' = seg ^ (e&7)).
//           buf1 head (@16384, 8KB) doubles as posS during classify.
//           After phase 2: SA 16 j-rows x 768 k bf16 stride SP=776 (24832 B),
//           cntL @24832 (8 j x 6 rel floats, 192 B; rows 8-15 never stored).
//   @32768  rel32: 8 j x 256 dwords, dword-index XOR swizzle (d ^ 2j), 8 KB.
// MFMA rows 8..15: duplicate masks via (m&7) -> finite junk, never stored.
// ---------------------------------------------------------------------------
#define SP 776

__global__ __launch_bounds__(512, 8)
void fused_kernel(const float* __restrict__ X, const float* __restrict__ pos,
                  const uint16_t* __restrict__ symT, const uint16_t* __restrict__ WtB,
                  const float* __restrict__ bias, const float* __restrict__ T4,
                  float* __restrict__ out) {
    __shared__ __align__(16) char smem[40960];
    float2*   posS  = (float2*)(smem + 16384);
    uint16_t* SA    = (uint16_t*)smem;
    float*    cntL  = (float*)(smem + 24832);
    uint32_t* rel32 = (uint32_t*)(smem + 32768);

    const int blk = blockIdx.x;
    const int b = blk & 7, jt = blk >> 3, j0 = jt * 8;
    const int tid = threadIdx.x;
    const int w = tid >> 6, lane = tid & 63, m = lane & 15, q = lane >> 4;

    const uint16_t* symTb = symT + ((size_t)b << 17);

    // --- B staging (R14-exact): wave w DMAs its own 16 e-rows, 64-i chunks ---
    // issue s, lane l: e = w*16 + s*8 + (l>>3); dest seg t = l&7 holds global
    // seg t ^ (e&7)  (consumer reads seg' = seg ^ (e&7)).
    int goff[2];
#pragma unroll
    for (int s = 0; s < 2; ++s) {
        int e = (w << 4) + (s << 3) + (lane >> 3);
        int t = lane & 7;
        goff[s] = (e << 10) + ((t ^ (e & 7)) << 3);   // halfword units; + c*64
    }

    auto issue_chunk = [&](int cidx, int bufsel) {
#ifdef HAVE_GLL
#pragma unroll
        for (int s = 0; s < 2; ++s) {
            const uint16_t* gp = symTb + goff[s] + cidx * 64;
            char* lp = smem + bufsel * 16384 + (w << 11) + (s << 10);  // wave-uniform
            typedef const __attribute__((address_space(1))) uint32_t gu32;
            typedef __attribute__((address_space(3))) uint32_t lu32;
            __builtin_amdgcn_global_load_lds((gu32*)gp, (lu32*)lp, 16, 0, 0);
        }
#else
#pragma unroll
        for (int s = 0; s < 2; ++s) {
            uint4 v = *(const uint4*)(symTb + goff[s] + cidx * 64);
            *(uint4*)(smem + bufsel * 16384 + (w << 11) + (s << 10) + lane * 16) = v;
        }
#endif
    };

    // ---- phase 0: chunk-0 DMA in flight under classify; stage positions ----
    issue_chunk(0, 0);
    const float2* pos2 = (const float2*)pos + ((size_t)b << 10);
    float2 p0 = pos2[tid], p1 = pos2[tid + 512];
    posS[tid] = p0;
    posS[tid + 512] = p1;
    BARRIER_LGKM();

    // ---- phase 1: classify 8 j x 1024 i -> one-hot bytes (0 on diagonal) ----
    {
        const int mm = tid & 7, grp = tid >> 3;     // grp 0..63: 16 i's each
        const int j = j0 + mm;
        const float2 pj = posS[j];
        uint32_t* dst = &rel32[mm * 256];
        const int sw = mm * 2;                      // dword-index XOR swizzle
#pragma unroll
        for (int s = 0; s < 4; ++s) {
            uint32_t word = 0;
#pragma unroll
            for (int qq = 0; qq < 4; ++qq) {
                int i = grp * 16 + s * 4 + qq;
                float2 pi = posS[i];
                float dx = pj.x - pi.x, dy = pj.y - pi.y;
                // faithful priority chain of _get_relation_type
                int r = (dy > 0.5f) ? 0
                      : (dy < -0.5f) ? 1
                      : (dx < -0.5f) ? 2
                      : (dx > 0.5f)  ? 3
                      : (fabsf(dx) < 0.3f && fabsf(dy) < 0.3f) ? 4
                      : 5;
                uint32_t oh = (i == j) ? 0u : (1u << r);
                word |= oh << (8 * qq);
            }
            dst[(grp * 4 + s) ^ sw] = word;
        }
    }
    BARRIER_LGKM();            // rel32 ready; posS dead

    // ---- phase 2: masked GEMM, 16 chunks of 64 i, barrier-free streaming ----
    f32x4 acc[5];
#pragma unroll
    for (int r = 0; r < 5; ++r) acc[r] = (f32x4){0.f, 0.f, 0.f, 0.f};

    const int E = (w << 4) + m;          // e-row owned by this lane
    const int bseg0 = q ^ (m & 7);       // ks=0 seg; ks=1 seg = (4+q)^(m&7)
    const int bseg1 = (4 + q) ^ (m & 7);
    const int m8 = m & 7;                // mask row (rows 8..15 alias 0..7)
    const int csw = m8 << 1;

    for (int c = 0; c < 16; ++c) {
        if (c < 15) {
            issue_chunk(c + 1, (c + 1) & 1);              // prefetch next chunk
            asm volatile("s_waitcnt vmcnt(2)" ::: "memory");  // chunk c landed
        } else {
            asm volatile("s_waitcnt vmcnt(0)" ::: "memory");
        }
        const char* bufc = smem + (c & 1) * 16384 + (w << 11) + (m << 7);
#pragma unroll
        for (int ks = 0; ks < 2; ++ks) {
            U4B bfr;
            bfr.u = *(const uint4*)(bufc + ((ks ? bseg1 : bseg0) << 4));
            uint2 cw = *(const uint2*)&rel32[m8 * 256 +
                           (((c << 4) + (ks << 3) + (q << 1)) ^ csw)];
            // byte -> halfword expansion (shared across r)
            uint32_t hx01 = __builtin_amdgcn_perm(cw.x, cw.x, 0x01010000u) & 0x00FF00FFu;
            uint32_t hx23 = __builtin_amdgcn_perm(cw.x, cw.x, 0x03030202u) & 0x00FF00FFu;
            uint32_t hy01 = __builtin_amdgcn_perm(cw.y, cw.y, 0x01010000u) & 0x00FF00FFu;
            uint32_t hy23 = __builtin_amdgcn_perm(cw.y, cw.y, 0x03030202u) & 0x00FF00FFu;
#pragma unroll
            for (int r = 0; r < 5; ++r) {
                const uint32_t rm = 0x00010001u << r;
                U4B a;
#ifdef OH_MUL24
                const uint32_t mc = 0x3F80u >> r;   // 2^r * mc == 0x3F80 (bf16 1.0)
                a.u.x = (uint32_t)__builtin_amdgcn_mul_u24((int)(hx01 & rm), (int)mc);
                a.u.y = (uint32_t)__builtin_amdgcn_mul_u24((int)(hx23 & rm), (int)mc);
                a.u.z = (uint32_t)__builtin_amdgcn_mul_u24((int)(hy01 & rm), (int)mc);
                a.u.w = (uint32_t)__builtin_amdgcn_mul_u24((int)(hy23 & rm), (int)mc);
#else
                uint32_t g2;
                g2 = hx01 & rm; a.u.x = (g2 << (14 - r)) - (g2 << (7 - r));
                g2 = hx23 & rm; a.u.y = (g2 << (14 - r)) - (g2 << (7 - r));
                g2 = hy01 & rm; a.u.z = (g2 << (14 - r)) - (g2 << (7 - r));
                g2 = hy23 & rm; a.u.w = (g2 << (14 - r)) - (g2 << (7 - r));
#endif
                acc[r] = __builtin_amdgcn_mfma_f32_16x16x32_bf16(a.b, bfr.b, acc[r], 0, 0, 0);
            }
        }
        // no barrier: wave only touches its own buffer regions.
    }
    BARRIER_LGKM();   // all waves done with staging before SA/cntL overwrite

    // ---- counts (staging now dead; cntL lives in its region): 8 waves x 1 j
    {
        const int j = tid >> 6, t = tid & 63;     // j = wave id 0..7
        const uint32_t* row = &rel32[j * 256 + t * 4];
        uint32_t s0 = 0, s1 = 0, s2 = 0, s3 = 0, s4 = 0;
#pragma unroll
        for (int k = 0; k < 4; ++k) {
            uint32_t wd = row[k];
            s0 += wd & 0x01010101u;        s1 += (wd >> 1) & 0x01010101u;
            s2 += (wd >> 2) & 0x01010101u; s3 += (wd >> 3) & 0x01010101u;
            s4 += (wd >> 4) & 0x01010101u;
        }
        int cnt[6];
        cnt[0] = (int)((s0 * 0x01010101u) >> 24);
        cnt[1] = (int)((s1 * 0x01010101u) >> 24);
        cnt[2] = (int)((s2 * 0x01010101u) >> 24);
        cnt[3] = (int)((s3 * 0x01010101u) >> 24);
        cnt[4] = (int)((s4 * 0x01010101u) >> 24);
#pragma unroll
        for (int off = 1; off < 64; off <<= 1)
#pragma unroll
            for (int r = 0; r < 5; ++r)
                cnt[r] += __shfl_xor(cnt[r], off, 64);   // full-wave reduce
        if (t == 0) {
#pragma unroll
            for (int r = 0; r < 5; ++r) cntL[j * 6 + r] = (float)cnt[r];
            cntL[j * 6 + 5] = (float)(1023 - cnt[0] - cnt[1] - cnt[2] - cnt[3] - cnt[4]);
        }
    }

    // ---- S -> SA (bf16) + S5 complement: S5 = T - sym[j] - sum_{r<5} S_r ----
#pragma unroll
    for (int r = 0; r < 5; ++r)
#pragma unroll
        for (int reg = 0; reg < 4; ++reg)
            SA[(q * 4 + reg) * SP + r * 128 + E] = f2bf(acc[r][reg]);
    {
        float ts = T4[((b << 2) + 0) * 128 + E] + T4[((b << 2) + 1) * 128 + E]
                 + T4[((b << 2) + 2) * 128 + E] + T4[((b << 2) + 3) * 128 + E];
#pragma unroll
        for (int reg = 0; reg < 4; ++reg) {
            // rows 8..15 alias j&7 (never stored); keeps the X-load in bounds
            float symj = X[((size_t)((b << 10) + j0 + (((q << 2) + reg) & 7)) << 7) + E];
            float s5 = ts - symj
                     - acc[0][reg] - acc[1][reg] - acc[2][reg] - acc[3][reg] - acc[4][reg];
            SA[(q * 4 + reg) * SP + 5 * 128 + E] = f2bf(s5);
        }
    }
    BARRIER_LGKM();

    // ---- phase 3: wave w owns e-slice [w*16,+16); full K=768 ----
    {
        f32x4 c3 = (f32x4){0.f, 0.f, 0.f, 0.f};
#pragma unroll
        for (int kb = 0; kb < 24; ++kb) {
            U4B af, bw;
            af.u = *(const uint4*)&SA[m * SP + kb * 32 + q * 8];
            bw.u = *(const uint4*)&WtB[((size_t)(kb * 128 + (w << 4) + m)) * 32 + q * 8];
            c3 = __builtin_amdgcn_mfma_f32_16x16x32_bf16(af.b, bw.b, c3, 0, 0, 0);
        }

        // ---- epilogue: + sym + cnt_r*bias, direct store (j < 8 only) ----
        const int e = (w << 4) + m;
        float be[6];
#pragma unroll
        for (int r = 0; r < 6; ++r) be[r] = bias[r * 128 + e];
#pragma unroll
        for (int reg = 0; reg < 4; ++reg) {
            const int j = q * 4 + reg;
            if (j < 8) {
                float add = c3[reg];
#pragma unroll
                for (int r = 0; r < 6; ++r) add += cntL[j * 6 + r] * be[r];
                size_t o = ((size_t)((b << 10) + j0 + j) << 7) + e;
                out[o] = X[o] + add;
            }
        }
    }
}

extern "C" void kernel_launch(void* const* d_in, const int* in_sizes, int n_in,
                              void* d_out, int out_size, void* d_ws, size_t ws_size,
                              hipStream_t stream) {
    const float* symbols   = (const float*)d_in[0];  // [8,1024,128]
    const float* positions = (const float*)d_in[1];  // [8,1024,2]
    const float* W         = (const float*)d_in[2];  // [6,128,128]
    const float* bias      = (const float*)d_in[3];  // [6,128]
    float* out             = (float*)d_out;          // [8,1024,128]

    char* ws = (char*)d_ws;
    uint16_t* symT = (uint16_t*)ws;                  // 8*128*1024 bf16 = 2,097,152 B
    uint16_t* WtB  = (uint16_t*)(ws + 2097152);      // 24*128*32 bf16 =   196,608 B
    float*    T4   = (float*)(ws + 2097152 + 196608);// 8*4*128 f32    =    16,384 B

    prep_kernel<<<384, 256, 0, stream>>>(symbols, W, symT, WtB, T4);
    fused_kernel<<<1024, 512, 0, stream>>>(symbols, positions, symT, WtB, bias, T4, out);
}

// Round 9
// 105.929 us; speedup vs baseline: 1.4730x; 1.0545x over previous
//
#include <hip/hip_runtime.h>
#include <stdint.h>

// out[b,j,:] = sym[b,j,:] + sum_{i!=j} (sym[b,i,:] @ W[rel(i,j)].T + bias[rel(i,j)])
// B=8, N=1024, D=128, 6 relations.
//
// Linearity rewrite:  agg[j] = sum_r (sum_{i!=j, rel=r} sym[i]) @ W[r].T + cnt_r(j)*bias[r]
//
// R19: R18 proved the stall is wave-hideable (2x work in 1.34x time at 2x
// TLP) but paid with redundant j-work. This round: full 16-j MFMA tile, no
// redundancy; i-range SPLIT ACROSS BLOCK PAIRS (h = i-half):
//   - fused_a: grid 1024 = 8b x 64jt x 2h; per block: classify 16j x 512i,
//     8 chunks of 64 i (HALF the serial chain), phase 3 on its half's S
//     (K=768, linear => partial agg), partial += cnt_half*bias, store to ws.
//     S5_h = T_h - (j-in-half? sym[j]) - sum_{r<5} S_r_h; T_h = 2 T4 quarters;
//     cnt5_h = 512 - diag_h - sum cnt_r_h. Chunk-loop byte-identical to R14.
//   - fused_b: out = sym + part0 + part1 (16 MB stream, ~3us). No cross-block
//     ordering assumptions (G16).
// LDS 40960 (staging 2x16K | SA 24832 + cntL; rel32 8K) + VGPR 32
// -> 4 blocks/CU (worst 3) = 8 waves/SIMD at zero redundant work.

typedef __attribute__((ext_vector_type(8))) short bf16x8;
typedef __attribute__((ext_vector_type(4))) float f32x4;
union U4B { uint4 u; bf16x8 b; };

#if defined(__has_builtin)
#  if __has_builtin(__builtin_amdgcn_global_load_lds)
#    define HAVE_GLL 1
#  endif
#  if __has_builtin(__builtin_amdgcn_mul_u24)
#    define OH_MUL24 1
#  endif
#endif

__device__ __forceinline__ uint16_t f2bf(float f) {
    union { float f; uint32_t u; } v; v.f = f;
    uint32_t u = v.u;
    uint32_t r = (u + 0x7FFFu + ((u >> 16) & 1u)) >> 16;  // RNE
    return (uint16_t)r;
}

// raw barrier: orders LDS only; never drains vmcnt (DMA stays in flight).
#define BARRIER_LGKM() do {                                   \
    asm volatile("s_waitcnt lgkmcnt(0)" ::: "memory");        \
    __builtin_amdgcn_s_barrier();                             \
    asm volatile("" ::: "memory");                            \
} while (0)

// ---------------------------------------------------------------------------
// prep: blocks 0..255: transpose X[b][i][e] fp32 -> symT[b][e][i] bf16 (64x64)
//       blocks 256..351: W[r][ep][e] fp32 -> WtB blocked bf16
//       blocks 352..383: T4[b][qq][e] = sum_{i in qq*256..+256} X[b][i][e]
// ---------------------------------------------------------------------------
__global__ __launch_bounds__(256)
void prep_kernel(const float* __restrict__ X, const float* __restrict__ W,
                 uint16_t* __restrict__ symT, uint16_t* __restrict__ WtB,
                 float* __restrict__ T4) {
    const int blk = blockIdx.x, tid = threadIdx.x;
    if (blk < 256) {
        __shared__ float T[64 * 65];
        const int b = blk & 7, z = blk >> 3, it = z & 15, et = z >> 4;
        const int i0 = it * 64, e0 = et * 64;
        const float4* Xf = (const float4*)X;
#pragma unroll
        for (int s = 0; s < 4; ++s) {
            int il = s * 16 + (tid >> 4), e4 = tid & 15;
            float4 v = Xf[((size_t)b << 15) + (size_t)((i0 + il) << 5) + (e0 >> 2) + e4];
            T[il * 65 + e4 * 4 + 0] = v.x;
            T[il * 65 + e4 * 4 + 1] = v.y;
            T[il * 65 + e4 * 4 + 2] = v.z;
            T[il * 65 + e4 * 4 + 3] = v.w;
        }
        __syncthreads();
#pragma unroll
        for (int s = 0; s < 4; ++s) {
            int el = s * 16 + (tid >> 4), il4 = tid & 15;
            uint16_t h0 = f2bf(T[(il4 * 4 + 0) * 65 + el]);
            uint16_t h1 = f2bf(T[(il4 * 4 + 1) * 65 + el]);
            uint16_t h2 = f2bf(T[(il4 * 4 + 2) * 65 + el]);
            uint16_t h3 = f2bf(T[(il4 * 4 + 3) * 65 + el]);
            uint2 pk = { (uint32_t)h0 | ((uint32_t)h1 << 16),
                         (uint32_t)h2 | ((uint32_t)h3 << 16) };
            *(uint2*)&symT[((size_t)b << 17) + ((size_t)(e0 + el) << 10) + i0 + il4 * 4] = pk;
        }
    } else if (blk < 352) {
        int g = (blk - 256) * 256 + tid;          // 0..24575 float4s of W
        float4 v = ((const float4*)W)[g];
        int r = g >> 12, rem = g & 4095, ep = rem >> 5, e4 = rem & 31;
        int kb = r * 4 + (e4 >> 3);               // k = r*128 + e4*4+t
        int kc = (e4 & 7) * 4;
        uint16_t h0 = f2bf(v.x), h1 = f2bf(v.y), h2 = f2bf(v.z), h3 = f2bf(v.w);
        uint2 pk = { (uint32_t)h0 | ((uint32_t)h1 << 16),
                     (uint32_t)h2 | ((uint32_t)h3 << 16) };
        *(uint2*)&WtB[((size_t)(kb * 128 + ep)) * 32 + kc] = pk;
    } else {
        // T4: per-b quarter column sums (fp32), 32 blocks = (b, quarter)
        const int z = blk - 352, bb = z >> 2, qq = z & 3;
        const int e = tid & 127, half = tid >> 7;
        const float* base = X + (((size_t)(bb << 10) + (qq << 8) + (half << 7)) << 7) + e;
        float s = 0.f;
#pragma unroll 8
        for (int itr = 0; itr < 128; ++itr) s += base[(size_t)itr << 7];
        __shared__ float red[256];
        red[tid] = s;
        __syncthreads();
        if (tid < 128) T4[(z << 7) + tid] = red[tid] + red[tid + 128];
    }
}

// ---------------------------------------------------------------------------
// fused_a: grid 1024 = 8b x 64jt x 2h (16 j, i in [h*512,(h+1)*512)).
// 512 thr = 8 waves. LDS 40960:
//   @0      B dbuf 2x16384 (64-i chunk; wave w owns [w*2048,+2048): 16 e-rows
//           x 128 B, 16B segs XOR-swizzled seg' = seg ^ (e&7)); buf1 head
//           (@16384, 8KB) = posS during classify. After phase 2: SA 16 j x
//           768 k bf16 stride SP=776 (24832 B) @0; cntL @24832 (16j x 6 f32).
//   @32768  rel32: 16 j x 128 dwords (its i-half), XOR swizzle (d ^ 2j), 8KB.
// ---------------------------------------------------------------------------
#define SP 776

__global__ __launch_bounds__(512, 8)
void fused_a(const float* __restrict__ X, const float* __restrict__ pos,
             const uint16_t* __restrict__ symT, const uint16_t* __restrict__ WtB,
             const float* __restrict__ bias, const float* __restrict__ T4,
             float* __restrict__ parts) {
    __shared__ __align__(16) char smem[40960];
    float2*   posS  = (float2*)(smem + 16384);
    uint16_t* SA    = (uint16_t*)smem;
    float*    cntL  = (float*)(smem + 24832);
    uint32_t* rel32 = (uint32_t*)(smem + 32768);

    const int blk = blockIdx.x;
    const int b = blk & 7, z = blk >> 3, jt = z >> 1, h = z & 1;
    const int j0 = jt * 16;
    const int tid = threadIdx.x;
    const int w = tid >> 6, lane = tid & 63, m = lane & 15, q = lane >> 4;

    // global base for this block's (b, i-half): halfword offset h*512
    const uint16_t* symTbh = symT + ((size_t)b << 17) + (h << 9);

    // --- B staging (R14-exact geometry): wave w DMAs its 16 e-rows ---
    int goff[2];
#pragma unroll
    for (int s = 0; s < 2; ++s) {
        int e = (w << 4) + (s << 3) + (lane >> 3);
        int t = lane & 7;
        goff[s] = (e << 10) + ((t ^ (e & 7)) << 3);   // halfword units; + c*64
    }

    auto issue_chunk = [&](int cidx, int bufsel) {
#ifdef HAVE_GLL
#pragma unroll
        for (int s = 0; s < 2; ++s) {
            const uint16_t* gp = symTbh + goff[s] + cidx * 64;
            char* lp = smem + bufsel * 16384 + (w << 11) + (s << 10);  // wave-uniform
            typedef const __attribute__((address_space(1))) uint32_t gu32;
            typedef __attribute__((address_space(3))) uint32_t lu32;
            __builtin_amdgcn_global_load_lds((gu32*)gp, (lu32*)lp, 16, 0, 0);
        }
#else
#pragma unroll
        for (int s = 0; s < 2; ++s) {
            uint4 v = *(const uint4*)(symTbh + goff[s] + cidx * 64);
            *(uint4*)(smem + bufsel * 16384 + (w << 11) + (s << 10) + lane * 16) = v;
        }
#endif
    };

    // ---- phase 0: chunk-0 DMA in flight under classify; stage positions ----
    issue_chunk(0, 0);
    const float2* pos2 = (const float2*)pos + ((size_t)b << 10);
    float2 p0 = pos2[tid], p1 = pos2[tid + 512];
    posS[tid] = p0;
    posS[tid + 512] = p1;
    BARRIER_LGKM();

    // ---- phase 1: classify 16 j x 512 i (this half) -> one-hot bytes ----
    {
        const int mm = tid & 15, grp = tid >> 4;    // grp 0..31: 16 i's each
        const int j = j0 + mm;
        const float2 pj = posS[j];
        uint32_t* dst = &rel32[mm * 128];
        const int sw = mm * 2;                      // dword-index XOR swizzle
#pragma unroll
        for (int s = 0; s < 4; ++s) {
            uint32_t word = 0;
#pragma unroll
            for (int qq = 0; qq < 4; ++qq) {
                int i = (h << 9) + grp * 16 + s * 4 + qq;
                float2 pi = posS[i];
                float dx = pj.x - pi.x, dy = pj.y - pi.y;
                // faithful priority chain of _get_relation_type
                int r = (dy > 0.5f) ? 0
                      : (dy < -0.5f) ? 1
                      : (dx < -0.5f) ? 2
                      : (dx > 0.5f)  ? 3
                      : (fabsf(dx) < 0.3f && fabsf(dy) < 0.3f) ? 4
                      : 5;
                uint32_t oh = (i == j) ? 0u : (1u << r);
                word |= oh << (8 * qq);
            }
            dst[(grp * 4 + s) ^ sw] = word;
        }
    }
    BARRIER_LGKM();            // rel32 ready; posS dead

    // ---- phase 2: masked GEMM, 8 chunks of 64 i, barrier-free streaming ----
    f32x4 acc[5];
#pragma unroll
    for (int r = 0; r < 5; ++r) acc[r] = (f32x4){0.f, 0.f, 0.f, 0.f};

    const int E = (w << 4) + m;          // e-row owned by this lane
    const int bseg0 = q ^ (m & 7);       // ks=0 seg; ks=1 seg = (4+q)^(m&7)
    const int bseg1 = (4 + q) ^ (m & 7);
    const int csw = m << 1;

    for (int c = 0; c < 8; ++c) {
        if (c < 7) {
            issue_chunk(c + 1, (c + 1) & 1);              // prefetch next chunk
            asm volatile("s_waitcnt vmcnt(2)" ::: "memory");  // chunk c landed
        } else {
            asm volatile("s_waitcnt vmcnt(0)" ::: "memory");
        }
        const char* bufc = smem + (c & 1) * 16384 + (w << 11) + (m << 7);
#pragma unroll
        for (int ks = 0; ks < 2; ++ks) {
            U4B bfr;
            bfr.u = *(const uint4*)(bufc + ((ks ? bseg1 : bseg0) << 4));
            uint2 cw = *(const uint2*)&rel32[m * 128 +
                           (((c << 4) + (ks << 3) + (q << 1)) ^ csw)];
            // byte -> halfword expansion (shared across r)
            uint32_t hx01 = __builtin_amdgcn_perm(cw.x, cw.x, 0x01010000u) & 0x00FF00FFu;
            uint32_t hx23 = __builtin_amdgcn_perm(cw.x, cw.x, 0x03030202u) & 0x00FF00FFu;
            uint32_t hy01 = __builtin_amdgcn_perm(cw.y, cw.y, 0x01010000u) & 0x00FF00FFu;
            uint32_t hy23 = __builtin_amdgcn_perm(cw.y, cw.y, 0x03030202u) & 0x00FF00FFu;
#pragma unroll
            for (int r = 0; r < 5; ++r) {
                const uint32_t rm = 0x00010001u << r;
                U4B a;
#ifdef OH_MUL24
                const uint32_t mc = 0x3F80u >> r;   // 2^r * mc == 0x3F80 (bf16 1.0)
                a.u.x = (uint32_t)__builtin_amdgcn_mul_u24((int)(hx01 & rm), (int)mc);
                a.u.y = (uint32_t)__builtin_amdgcn_mul_u24((int)(hx23 & rm), (int)mc);
                a.u.z = (uint32_t)__builtin_amdgcn_mul_u24((int)(hy01 & rm), (int)mc);
                a.u.w = (uint32_t)__builtin_amdgcn_mul_u24((int)(hy23 & rm), (int)mc);
#else
                uint32_t g2;
                g2 = hx01 & rm; a.u.x = (g2 << (14 - r)) - (g2 << (7 - r));
                g2 = hx23 & rm; a.u.y = (g2 << (14 - r)) - (g2 << (7 - r));
                g2 = hy01 & rm; a.u.z = (g2 << (14 - r)) - (g2 << (7 - r));
                g2 = hy23 & rm; a.u.w = (g2 << (14 - r)) - (g2 << (7 - r));
#endif
                acc[r] = __builtin_amdgcn_mfma_f32_16x16x32_bf16(a.b, bfr.b, acc[r], 0, 0, 0);
            }
        }
        // no barrier: wave only touches its own buffer regions.
    }
    BARRIER_LGKM();   // all waves done with staging before SA/cntL overwrite

    // ---- counts for this half (staging dead; cntL in its region) ----
    const int diag = ((jt >> 5) == h) ? 1 : 0;   // block's j-range in this i-half?
    {
        const int j = tid >> 5, t = tid & 31;    // 16 j x 32 threads
        const uint32_t* row = &rel32[j * 128 + t * 4];
        uint32_t s0 = 0, s1 = 0, s2 = 0, s3 = 0, s4 = 0;
#pragma unroll
        for (int k = 0; k < 4; ++k) {
            uint32_t wd = row[k];
            s0 += wd & 0x01010101u;        s1 += (wd >> 1) & 0x01010101u;
            s2 += (wd >> 2) & 0x01010101u; s3 += (wd >> 3) & 0x01010101u;
            s4 += (wd >> 4) & 0x01010101u;
        }
        int cnt[6];
        cnt[0] = (int)((s0 * 0x01010101u) >> 24);
        cnt[1] = (int)((s1 * 0x01010101u) >> 24);
        cnt[2] = (int)((s2 * 0x01010101u) >> 24);
        cnt[3] = (int)((s3 * 0x01010101u) >> 24);
        cnt[4] = (int)((s4 * 0x01010101u) >> 24);
#pragma unroll
        for (int off = 1; off < 32; off <<= 1)
#pragma unroll
            for (int r = 0; r < 5; ++r)
                cnt[r] += __shfl_xor(cnt[r], off, 64);   // 32-aligned groups
        if (t == 0) {
#pragma unroll
            for (int r = 0; r < 5; ++r) cntL[j * 6 + r] = (float)cnt[r];
            cntL[j * 6 + 5] = (float)(512 - diag - cnt[0] - cnt[1] - cnt[2] - cnt[3] - cnt[4]);
        }
    }

    // ---- S -> SA (bf16) + S5 complement for this half ----
#pragma unroll
    for (int r = 0; r < 5; ++r)
#pragma unroll
        for (int reg = 0; reg < 4; ++reg)
            SA[(q * 4 + reg) * SP + r * 128 + E] = f2bf(acc[r][reg]);
    {
        float ts = T4[(((b << 2) + (h << 1)) << 7) + E]
                 + T4[(((b << 2) + (h << 1) + 1) << 7) + E];
#pragma unroll
        for (int reg = 0; reg < 4; ++reg) {
            const int j = (q << 2) + reg;
            float symj = diag ? X[((size_t)((b << 10) + j0 + j) << 7) + E] : 0.f;
            float s5 = ts - symj
                     - acc[0][reg] - acc[1][reg] - acc[2][reg] - acc[3][reg] - acc[4][reg];
            SA[j * SP + 5 * 128 + E] = f2bf(s5);
        }
    }
    BARRIER_LGKM();

    // ---- phase 3: wave w owns e-slice [w*16,+16); K=768 on this half's S ----
    {
        f32x4 c3 = (f32x4){0.f, 0.f, 0.f, 0.f};
#pragma unroll
        for (int kb = 0; kb < 24; ++kb) {
            U4B af, bw;
            af.u = *(const uint4*)&SA[m * SP + kb * 32 + q * 8];
            bw.u = *(const uint4*)&WtB[((size_t)(kb * 128 + (w << 4) + m)) * 32 + q * 8];
            c3 = __builtin_amdgcn_mfma_f32_16x16x32_bf16(af.b, bw.b, c3, 0, 0, 0);
        }

        // ---- epilogue: partial = agg_half + cnt_half*bias -> ws ----
        const int e = (w << 4) + m;
        float be[6];
#pragma unroll
        for (int r = 0; r < 6; ++r) be[r] = bias[r * 128 + e];
        float* part = parts + ((size_t)h << 20);   // h * 8*1024*128
#pragma unroll
        for (int reg = 0; reg < 4; ++reg) {
            const int j = q * 4 + reg;
            float add = c3[reg];
#pragma unroll
            for (int r = 0; r < 6; ++r) add += cntL[j * 6 + r] * be[r];
            part[((size_t)((b << 10) + j0 + j) << 7) + e] = add;
        }
    }
}

// ---------------------------------------------------------------------------
// fused_b: out = sym + part0 + part1  (streaming float4, 16 MB total)
// ---------------------------------------------------------------------------
__global__ __launch_bounds__(256)
void fused_b(const float* __restrict__ X, const float* __restrict__ parts,
             float* __restrict__ out) {
    const int g = blockIdx.x * 256 + threadIdx.x;   // 262144 float4s
    const float4* X4 = (const float4*)X;
    const float4* P0 = (const float4*)parts;
    const float4* P1 = (const float4*)(parts + (1u << 20));
    float4 x = X4[g], a = P0[g], c = P1[g];
    float4 o = { x.x + a.x + c.x, x.y + a.y + c.y,
                 x.z + a.z + c.z, x.w + a.w + c.w };
    ((float4*)out)[g] = o;
}

extern "C" void kernel_launch(void* const* d_in, const int* in_sizes, int n_in,
                              void* d_out, int out_size, void* d_ws, size_t ws_size,
                              hipStream_t stream) {
    const float* symbols   = (const float*)d_in[0];  // [8,1024,128]
    const float* positions = (const float*)d_in[1];  // [8,1024,2]
    const float* W         = (const float*)d_in[2];  // [6,128,128]
    const float* bias      = (const float*)d_in[3];  // [6,128]
    float* out             = (float*)d_out;          // [8,1024,128]

    char* ws = (char*)d_ws;
    uint16_t* symT = (uint16_t*)ws;                  // 8*128*1024 bf16 = 2,097,152 B
    uint16_t* WtB  = (uint16_t*)(ws + 2097152);      // 24*128*32 bf16 =   196,608 B
    float*    T4   = (float*)(ws + 2097152 + 196608);// 8*4*128 f32    =    16,384 B
    float*    part = (float*)(ws + 2310144);         // 2 x 4 MB partials

    prep_kernel<<<384, 256, 0, stream>>>(symbols, W, symT, WtB, T4);
    fused_a<<<1024, 512, 0, stream>>>(symbols, positions, symT, WtB, bias, T4, part);
    fused_b<<<1024, 256, 0, stream>>>(symbols, part, out);
}

// Round 10
// 97.133 us; speedup vs baseline: 1.6064x; 1.0906x over previous
//
#include <hip/hip_runtime.h>
#include <stdint.h>

// out[b,j,:] = sym[b,j,:] + sum_{i!=j} (sym[b,i,:] @ W[rel(i,j)].T + bias[rel(i,j)])
// B=8, N=1024, D=128, 6 relations.
//
// Linearity rewrite:  agg[j] = sum_r (sum_{i!=j, rel=r} sym[i]) @ W[r].T + cnt_r(j)*bias[r]
//
// R20: model reconciliation across R0/R14/R15/R18/R19: the harness's 256MiB
// poison fill WIPES L2+L3 before every timed iteration -> fused runs cold
// (R15 rep-1 ~50us vs steady ~30us; R0 measured 44 cold). The cold-warm gap
// is DMA-latency exposure: R14's double buffer keeps only 1 chunk (2 issues)
// in flight -> ~250cy unhidden stall x 16 chunks/wave. Fix at fixed TLP:
// TRIPLE-buffered staging, depth-2 prefetch: at chunk c issue chunk c+2,
// wait vmcnt(4) (2 chunks always in flight; drained only at the tail).
// Everything else byte-identical to R14 (passed): classify, counts,
// mul24 mask expansion, 5r + S5 complement, K=768 phase 3, direct epilogue.
// LDS 65920 B -> 2 blocks/CU. posS -> buf2 head (dead before chunk-2 DMA);
// chunk-1 issue hides under counts; pos loads precede DMA issue so the
// compiler's pos-wait doesn't drain the staging queue.

typedef __attribute__((ext_vector_type(8))) short bf16x8;
typedef __attribute__((ext_vector_type(4))) float f32x4;
union U4B { uint4 u; bf16x8 b; };

#if defined(__has_builtin)
#  if __has_builtin(__builtin_amdgcn_global_load_lds)
#    define HAVE_GLL 1
#  endif
#  if __has_builtin(__builtin_amdgcn_mul_u24)
#    define OH_MUL24 1
#  endif
#endif

__device__ __forceinline__ uint16_t f2bf(float f) {
    union { float f; uint32_t u; } v; v.f = f;
    uint32_t u = v.u;
    uint32_t r = (u + 0x7FFFu + ((u >> 16) & 1u)) >> 16;  // RNE
    return (uint16_t)r;
}

// raw barrier: orders LDS only; never drains vmcnt (DMA stays in flight).
#define BARRIER_LGKM() do {                                   \
    asm volatile("s_waitcnt lgkmcnt(0)" ::: "memory");        \
    __builtin_amdgcn_s_barrier();                             \
    asm volatile("" ::: "memory");                            \
} while (0)

// ---------------------------------------------------------------------------
// prep: blocks 0..255: transpose X[b][i][e] fp32 -> symT[b][e][i] bf16 (64x64)
//       blocks 256..351: W[r][ep][e] fp32 -> WtB blocked bf16
//       blocks 352..383: T4[b][qq][e] = sum_{i in qq*256..+256} X[b][i][e]
// ---------------------------------------------------------------------------
__global__ __launch_bounds__(256)
void prep_kernel(const float* __restrict__ X, const float* __restrict__ W,
                 uint16_t* __restrict__ symT, uint16_t* __restrict__ WtB,
                 float* __restrict__ T4) {
    const int blk = blockIdx.x, tid = threadIdx.x;
    if (blk < 256) {
        __shared__ float T[64 * 65];
        const int b = blk & 7, z = blk >> 3, it = z & 15, et = z >> 4;
        const int i0 = it * 64, e0 = et * 64;
        const float4* Xf = (const float4*)X;
#pragma unroll
        for (int s = 0; s < 4; ++s) {
            int il = s * 16 + (tid >> 4), e4 = tid & 15;
            float4 v = Xf[((size_t)b << 15) + (size_t)((i0 + il) << 5) + (e0 >> 2) + e4];
            T[il * 65 + e4 * 4 + 0] = v.x;
            T[il * 65 + e4 * 4 + 1] = v.y;
            T[il * 65 + e4 * 4 + 2] = v.z;
            T[il * 65 + e4 * 4 + 3] = v.w;
        }
        __syncthreads();
#pragma unroll
        for (int s = 0; s < 4; ++s) {
            int el = s * 16 + (tid >> 4), il4 = tid & 15;
            uint16_t h0 = f2bf(T[(il4 * 4 + 0) * 65 + el]);
            uint16_t h1 = f2bf(T[(il4 * 4 + 1) * 65 + el]);
            uint16_t h2 = f2bf(T[(il4 * 4 + 2) * 65 + el]);
            uint16_t h3 = f2bf(T[(il4 * 4 + 3) * 65 + el]);
            uint2 pk = { (uint32_t)h0 | ((uint32_t)h1 << 16),
                         (uint32_t)h2 | ((uint32_t)h3 << 16) };
            *(uint2*)&symT[((size_t)b << 17) + ((size_t)(e0 + el) << 10) + i0 + il4 * 4] = pk;
        }
    } else if (blk < 352) {
        int g = (blk - 256) * 256 + tid;          // 0..24575 float4s of W
        float4 v = ((const float4*)W)[g];
        int r = g >> 12, rem = g & 4095, ep = rem >> 5, e4 = rem & 31;
        int kb = r * 4 + (e4 >> 3);               // k = r*128 + e4*4+t
        int kc = (e4 & 7) * 4;
        uint16_t h0 = f2bf(v.x), h1 = f2bf(v.y), h2 = f2bf(v.z), h3 = f2bf(v.w);
        uint2 pk = { (uint32_t)h0 | ((uint32_t)h1 << 16),
                     (uint32_t)h2 | ((uint32_t)h3 << 16) };
        *(uint2*)&WtB[((size_t)(kb * 128 + ep)) * 32 + kc] = pk;
    } else {
        // T4: per-b quarter column sums (fp32), 32 blocks = (b, quarter)
        const int z = blk - 352, bb = z >> 2, qq = z & 3;
        const int e = tid & 127, half = tid >> 7;
        const float* base = X + (((size_t)(bb << 10) + (qq << 8) + (half << 7)) << 7) + e;
        float s = 0.f;
#pragma unroll 8
        for (int itr = 0; itr < 128; ++itr) s += base[(size_t)itr << 7];
        __shared__ float red[256];
        red[tid] = s;
        __syncthreads();
        if (tid < 128) T4[(z << 7) + tid] = red[tid] + red[tid + 128];
    }
}

// ---------------------------------------------------------------------------
// fused kernel: grid 512 = 8b x 64jt (16 j per block), 512 thr = 8 waves.
// LDS map (65920 B -> 2 blocks/CU):
//   @0      B TRIPLE buffer: 3 x 16384 (64-i chunk; wave w owns
//           [w*2048,+2048): 16 e-rows x 128 B, 16B segs XOR-swizzled
//           seg' = seg ^ (e&7)). buf2 head (@32768, 8KB) = posS during
//           classify (dead before the first chunk-2 DMA). After phase 2
//           the region holds SA: 16 j x 768 k bf16, stride SP=776 (24832 B).
//   @49152  rel32: 16 j x 256 dwords, dword-index XOR swizzle (d ^ 2j), 16KB.
//   @65536  cntL: 16 j x 6 relations, float, 384 B.
// ---------------------------------------------------------------------------
#define SP 776

__global__ __launch_bounds__(512, 4)
void fused_kernel(const float* __restrict__ X, const float* __restrict__ pos,
                  const uint16_t* __restrict__ symT, const uint16_t* __restrict__ WtB,
                  const float* __restrict__ bias, const float* __restrict__ T4,
                  float* __restrict__ out) {
    __shared__ __align__(16) char smem[65920];
    float2*   posS  = (float2*)(smem + 32768);
    uint16_t* SA    = (uint16_t*)smem;
    uint32_t* rel32 = (uint32_t*)(smem + 49152);
    float*    cntL  = (float*)(smem + 65536);

    const int blk = blockIdx.x;
    const int b = blk & 7, jt = blk >> 3, j0 = jt * 16;
    const int tid = threadIdx.x;
    const int w = tid >> 6, lane = tid & 63, m = lane & 15, q = lane >> 4;

    const uint16_t* symTb = symT + ((size_t)b << 17);

    // --- B staging (R14-exact geometry): wave w DMAs its own 16 e-rows,
    //     64-i chunks, 2 issues/chunk; dest seg t holds global seg t^(e&7).
    int goff[2];
#pragma unroll
    for (int s = 0; s < 2; ++s) {
        int e = (w << 4) + (s << 3) + (lane >> 3);
        int t = lane & 7;
        goff[s] = (e << 10) + ((t ^ (e & 7)) << 3);   // halfword units; + c*64
    }

    auto issue_chunk = [&](int cidx, int bufsel) {
#ifdef HAVE_GLL
#pragma unroll
        for (int s = 0; s < 2; ++s) {
            const uint16_t* gp = symTb + goff[s] + cidx * 64;
            char* lp = smem + bufsel * 16384 + (w << 11) + (s << 10);  // wave-uniform
            typedef const __attribute__((address_space(1))) uint32_t gu32;
            typedef __attribute__((address_space(3))) uint32_t lu32;
            __builtin_amdgcn_global_load_lds((gu32*)gp, (lu32*)lp, 16, 0, 0);
        }
#else
#pragma unroll
        for (int s = 0; s < 2; ++s) {
            uint4 v = *(const uint4*)(symTb + goff[s] + cidx * 64);
            *(uint4*)(smem + bufsel * 16384 + (w << 11) + (s << 10) + lane * 16) = v;
        }
#endif
    };

    // ---- phase 0: pos loads FIRST (their waits then don't drain the DMA
    //      queue), chunk-0 DMA in flight under classify, posS in buf2 head ----
    const float2* pos2 = (const float2*)pos + ((size_t)b << 10);
    float2 p0 = pos2[tid], p1 = pos2[tid + 512];
    issue_chunk(0, 0);
    posS[tid] = p0;
    posS[tid + 512] = p1;
    BARRIER_LGKM();

    // ---- phase 1: classify 16 j x 1024 i -> one-hot bytes (0 on diagonal) ----
    {
        const int mm = tid & 15, grp = tid >> 4;    // grp 0..31: 32 i's each
        const int j = j0 + mm;
        const float2 pj = posS[j];
        uint32_t* dst = &rel32[mm * 256];
        const int sw = mm * 2;                      // dword-index XOR swizzle
#pragma unroll
        for (int s = 0; s < 8; ++s) {
            uint32_t word = 0;
#pragma unroll
            for (int qq = 0; qq < 4; ++qq) {
                int i = grp * 32 + s * 4 + qq;
                float2 pi = posS[i];
                float dx = pj.x - pi.x, dy = pj.y - pi.y;
                // faithful priority chain of _get_relation_type
                int r = (dy > 0.5f) ? 0
                      : (dy < -0.5f) ? 1
                      : (dx < -0.5f) ? 2
                      : (dx > 0.5f)  ? 3
                      : (fabsf(dx) < 0.3f && fabsf(dy) < 0.3f) ? 4
                      : 5;
                uint32_t oh = (i == j) ? 0u : (1u << r);
                word |= oh << (8 * qq);
            }
            dst[(grp * 8 + s) ^ sw] = word;
        }
    }
    BARRIER_LGKM();            // rel32 ready; posS dead (buf2 now DMA-able)

    // chunk-1 DMA issued here: its latency hides under the counts block
    issue_chunk(1, 1);

    // ---- counts: cnt_r(j) from rel32 (swizzle is row-internal, popcount-
    //      invariant); cnt5 = 1023 - sum. Epilogue visibility via barriers.
    {
        const int j = tid >> 5, t = tid & 31;
        const uint32_t* row = &rel32[j * 256 + t * 8];
        uint32_t s0 = 0, s1 = 0, s2 = 0, s3 = 0, s4 = 0;
#pragma unroll
        for (int k = 0; k < 8; ++k) {
            uint32_t wd = row[k];
            s0 += wd & 0x01010101u;        s1 += (wd >> 1) & 0x01010101u;
            s2 += (wd >> 2) & 0x01010101u; s3 += (wd >> 3) & 0x01010101u;
            s4 += (wd >> 4) & 0x01010101u;
        }
        int cnt[6];
        cnt[0] = (int)((s0 * 0x01010101u) >> 24);
        cnt[1] = (int)((s1 * 0x01010101u) >> 24);
        cnt[2] = (int)((s2 * 0x01010101u) >> 24);
        cnt[3] = (int)((s3 * 0x01010101u) >> 24);
        cnt[4] = (int)((s4 * 0x01010101u) >> 24);
#pragma unroll
        for (int off = 1; off < 32; off <<= 1)
#pragma unroll
            for (int r = 0; r < 5; ++r)
                cnt[r] += __shfl_xor(cnt[r], off, 64);   // 32-aligned groups
        if (t == 0) {
#pragma unroll
            for (int r = 0; r < 5; ++r) cntL[j * 6 + r] = (float)cnt[r];
            cntL[j * 6 + 5] = (float)(1023 - cnt[0] - cnt[1] - cnt[2] - cnt[3] - cnt[4]);
        }
    }

    // ---- phase 2: masked GEMM, 16 chunks of 64 i, TRIPLE-buffered,
    //      depth-2 prefetch: issue c+2, wait vmcnt(4) (2 chunks in flight) ----
    f32x4 acc[5];
#pragma unroll
    for (int r = 0; r < 5; ++r) acc[r] = (f32x4){0.f, 0.f, 0.f, 0.f};

    const int E = (w << 4) + m;          // e-row owned by this lane
    const int bseg0 = q ^ (m & 7);       // ks=0 seg; ks=1 seg = (4+q)^(m&7)
    const int bseg1 = (4 + q) ^ (m & 7);
    const int csw = m << 1;

    for (int c = 0; c < 16; ++c) {
        if (c < 14) {
            issue_chunk(c + 2, (c + 2) % 3);              // prefetch 2 ahead
            asm volatile("s_waitcnt vmcnt(4)" ::: "memory");  // chunk c landed
        } else if (c == 14) {
            asm volatile("s_waitcnt vmcnt(2)" ::: "memory");  // chunk 14 landed
        } else {
            asm volatile("s_waitcnt vmcnt(0)" ::: "memory");  // chunk 15 landed
        }
        const char* bufc = smem + (c % 3) * 16384 + (w << 11) + (m << 7);
#pragma unroll
        for (int ks = 0; ks < 2; ++ks) {
            U4B bfr;
            bfr.u = *(const uint4*)(bufc + ((ks ? bseg1 : bseg0) << 4));
            uint2 cw = *(const uint2*)&rel32[m * 256 +
                           (((c << 4) + (ks << 3) + (q << 1)) ^ csw)];
            // byte -> halfword expansion (shared across r)
            uint32_t hx01 = __builtin_amdgcn_perm(cw.x, cw.x, 0x01010000u) & 0x00FF00FFu;
            uint32_t hx23 = __builtin_amdgcn_perm(cw.x, cw.x, 0x03030202u) & 0x00FF00FFu;
            uint32_t hy01 = __builtin_amdgcn_perm(cw.y, cw.y, 0x01010000u) & 0x00FF00FFu;
            uint32_t hy23 = __builtin_amdgcn_perm(cw.y, cw.y, 0x03030202u) & 0x00FF00FFu;
#pragma unroll
            for (int r = 0; r < 5; ++r) {
                const uint32_t rm = 0x00010001u << r;
                U4B a;
#ifdef OH_MUL24
                const uint32_t mc = 0x3F80u >> r;   // 2^r * mc == 0x3F80 (bf16 1.0)
                a.u.x = (uint32_t)__builtin_amdgcn_mul_u24((int)(hx01 & rm), (int)mc);
                a.u.y = (uint32_t)__builtin_amdgcn_mul_u24((int)(hx23 & rm), (int)mc);
                a.u.z = (uint32_t)__builtin_amdgcn_mul_u24((int)(hy01 & rm), (int)mc);
                a.u.w = (uint32_t)__builtin_amdgcn_mul_u24((int)(hy23 & rm), (int)mc);
#else
                uint32_t g2;
                g2 = hx01 & rm; a.u.x = (g2 << (14 - r)) - (g2 << (7 - r));
                g2 = hx23 & rm; a.u.y = (g2 << (14 - r)) - (g2 << (7 - r));
                g2 = hy01 & rm; a.u.z = (g2 << (14 - r)) - (g2 << (7 - r));
                g2 = hy23 & rm; a.u.w = (g2 << (14 - r)) - (g2 << (7 - r));
#endif
                acc[r] = __builtin_amdgcn_mfma_f32_16x16x32_bf16(a.b, bfr.b, acc[r], 0, 0, 0);
            }
        }
        // no barrier: wave only touches its own buffer regions; buf reuse
        // distance is 3 (chunk c+2's writes target buf consumed at c-1).
    }
    BARRIER_LGKM();   // all waves done with staging before SA overwrites

    // ---- S -> SA (bf16) + S5 complement: S5 = T - sym[j] - sum_{r<5} S_r ----
#pragma unroll
    for (int r = 0; r < 5; ++r)
#pragma unroll
        for (int reg = 0; reg < 4; ++reg)
            SA[(q * 4 + reg) * SP + r * 128 + E] = f2bf(acc[r][reg]);
    {
        float ts = T4[((b << 2) + 0) * 128 + E] + T4[((b << 2) + 1) * 128 + E]
                 + T4[((b << 2) + 2) * 128 + E] + T4[((b << 2) + 3) * 128 + E];
#pragma unroll
        for (int reg = 0; reg < 4; ++reg) {
            float symj = X[((size_t)((b << 10) + j0 + (q << 2) + reg) << 7) + E];
            float s5 = ts - symj
                     - acc[0][reg] - acc[1][reg] - acc[2][reg] - acc[3][reg] - acc[4][reg];
            SA[(q * 4 + reg) * SP + 5 * 128 + E] = f2bf(s5);
        }
    }
    BARRIER_LGKM();

    // ---- phase 3: wave w owns e-slice [w*16,+16); full K=768 ----
    {
        f32x4 c3 = (f32x4){0.f, 0.f, 0.f, 0.f};
#pragma unroll
        for (int kb = 0; kb < 24; ++kb) {
            U4B af, bw;
            af.u = *(const uint4*)&SA[m * SP + kb * 32 + q * 8];
            bw.u = *(const uint4*)&WtB[((size_t)(kb * 128 + (w << 4) + m)) * 32 + q * 8];
            c3 = __builtin_amdgcn_mfma_f32_16x16x32_bf16(af.b, bw.b, c3, 0, 0, 0);
        }

        // ---- epilogue: + sym + cnt_r*bias, direct store ----
        const int e = (w << 4) + m;
        float be[6];
#pragma unroll
        for (int r = 0; r < 6; ++r) be[r] = bias[r * 128 + e];
#pragma unroll
        for (int reg = 0; reg < 4; ++reg) {
            const int j = q * 4 + reg;
            float add = c3[reg];
#pragma unroll
            for (int r = 0; r < 6; ++r) add += cntL[j * 6 + r] * be[r];
            size_t o = ((size_t)((b << 10) + j0 + j) << 7) + e;
            out[o] = X[o] + add;
        }
    }
}

extern "C" void kernel_launch(void* const* d_in, const int* in_sizes, int n_in,
                              void* d_out, int out_size, void* d_ws, size_t ws_size,
                              hipStream_t stream) {
    const float* symbols   = (const float*)d_in[0];  // [8,1024,128]
    const float* positions = (const float*)d_in[1];  // [8,1024,2]
    const float* W         = (const float*)d_in[2];  // [6,128,128]
    const float* bias      = (const float*)d_in[3];  // [6,128]
    float* out             = (float*)d_out;          // [8,1024,128]

    char* ws = (char*)d_ws;
    uint16_t* symT = (uint16_t*)ws;                  // 8*128*1024 bf16 = 2,097,152 B
    uint16_t* WtB  = (uint16_t*)(ws + 2097152);      // 24*128*32 bf16 =   196,608 B
    float*    T4   = (float*)(ws + 2097152 + 196608);// 8*4*128 f32    =    16,384 B

    prep_kernel<<<384, 256, 0, stream>>>(symbols, W, symT, WtB, T4);
    fused_kernel<<<512, 512, 0, stream>>>(symbols, positions, symT, WtB, bias, T4, out);
}